// Round 9
// baseline (477.826 us; speedup 1.0000x reference)
//
#include <hip/hip_runtime.h>

typedef __bf16 bf16;
typedef __bf16 bf16x8 __attribute__((ext_vector_type(8)));
typedef __bf16 bf16x4 __attribute__((ext_vector_type(4)));
typedef float f32x4 __attribute__((ext_vector_type(4)));
typedef unsigned int u32;
typedef unsigned short u16;

#define MFMA_BF16 __builtin_amdgcn_mfma_f32_16x16x32_bf16

#define GLOAD_LDS(g, l)                                        \
  __builtin_amdgcn_global_load_lds(                            \
      (__attribute__((address_space(1))) void*)(g),            \
      (__attribute__((address_space(3))) void*)(l), 16, 0, 0)

// ---------------------------------------------------------------- utilities
__global__ void cvt_f32_bf16(const float* __restrict__ in, bf16* __restrict__ out, int n) {
  int i = (blockIdx.x * blockDim.x + threadIdx.x) * 4;
  if (i >= n) return;
  float4 v = *(const float4*)(in + i);
  bf16x4 o;
  o[0] = (bf16)v.x; o[1] = (bf16)v.y; o[2] = (bf16)v.z; o[3] = (bf16)v.w;
  *(bf16x4*)(out + i) = o;
}

// W [K][N] fp32 -> Wt [N][K] bf16
__global__ void transpose_w(const float* __restrict__ w, bf16* __restrict__ wt, int K, int N) {
  __shared__ float tile[32][33];
  int n0 = blockIdx.x * 32, k0 = blockIdx.y * 32;
  int t = threadIdx.x;
  int c = t & 31, r = t >> 5;
#pragma unroll
  for (int i = 0; i < 4; i++)
    tile[r + i * 8][c] = w[(size_t)(k0 + r + i * 8) * N + n0 + c];
  __syncthreads();
#pragma unroll
  for (int i = 0; i < 4; i++)
    wt[(size_t)(n0 + r + i * 8) * K + k0 + c] = (bf16)tile[c][r + i * 8];
}

__device__ inline float gelu_exact(float x) {
  return 0.5f * x * (1.0f + erff(x * 0.70710678118654752f));
}

// ---------------------------------------------------------------- GEMM
// 256x(NF*64) tile, BK=32, 512 threads = 8 waves (2M x 4N), acc[8][NF].
// RING-3 LDS (3 x 32KB-class slots) -> single barrier per K-tile:
//   [vmcnt(LPT); barrier; stage(t+2 -> slot(t+2)%3); 12 ds_read_b128;
//    lgkmcnt(0); setprio(1); 32-MFMA independent run; setprio(0)]
// WAR-free: stage(t+2) targets the slot last read at tile t-1; all waves'
// t-1 reads are lgkm-drained before their tile-t barrier arrival. vmcnt is
// counted (LPT = per-wave loads of the NEXT tile), never 0 in-loop.
// Swizzle: read chunk ^= (row>>1)&3 (R5-verified 0-conflict), inverse
// pre-applied on the per-lane GLOBAL source; LDS dest stays lane-linear.
template <int MODE, int NF>
__global__ __launch_bounds__(512, 1) void gemm_bt(
    const bf16* __restrict__ A, const bf16* __restrict__ Bt,
    bf16* __restrict__ outb, float* __restrict__ outf,
    const float* __restrict__ resid, int K, int N) {
  __shared__ __align__(16) bf16 As[3][256 * 32];
  __shared__ __align__(16) bf16 Bs[3][NF * 64 * 32];
  const int tid = threadIdx.x;
  const int lane = tid & 63, w = tid >> 6;
  const int g = lane >> 4, l15 = lane & 15;
  const int wm = w >> 2, wn = w & 3;

  // XCD-chunked mapping; M-tiles (32) fastest within each XCD chunk
  const int cpx = (int)gridDim.x >> 3;
  const int widx = ((int)blockIdx.x & 7) * cpx + ((int)blockIdx.x >> 3);
  const int m0 = (widx & 31) * 256, n0 = (widx >> 5) * (NF * 64);

  f32x4 acc[8][NF] = {};

  // staging: thread covers row = tid>>2 (128 rows/set), 16B chunk tid&3,
  // chunk pre-swizzled so that LDS-linear + swizzled-read match.
  const int srow = tid >> 2;
  const int schunk = (tid & 3) ^ ((tid >> 3) & 3);
  const char* gA = (const char*)A;
  const char* gB = (const char*)Bt;
  const size_t aOff = ((size_t)(m0 + srow) * K + schunk * 8) * 2;
  const size_t bOff = ((size_t)(n0 + srow) * K + schunk * 8) * 2;

  auto stage = [&](int kt, int slot) {
    const size_t kb = (size_t)kt * 64;  // kt*32 elems * 2B
    GLOAD_LDS(gA + aOff + kb, &As[slot][(w * 16) * 32]);
    GLOAD_LDS(gA + aOff + (size_t)128 * K * 2 + kb, &As[slot][(128 + w * 16) * 32]);
    GLOAD_LDS(gB + bOff + kb, &Bs[slot][(w * 16) * 32]);
    if constexpr (NF == 4)
      GLOAD_LDS(gB + bOff + (size_t)128 * K * 2 + kb, &Bs[slot][(128 + w * 16) * 32]);
  };

  // fragment read offsets (bytes): row*64 + swizzled 16B chunk
  const int rsw = (g ^ ((l15 >> 1) & 3)) << 4;
  const int rdA = (wm * 128 + l15) * 64 + rsw;
  const int rdB = (wn * 16 * NF + l15) * 64 + rsw;

  const int T = K >> 5;
  stage(0, 0);
  stage(1, 1);

  int slot = 0;
  for (int t = 0; t < T; ++t) {
    if (t < T - 1) {
      if constexpr (NF == 4) asm volatile("s_waitcnt vmcnt(4)" ::: "memory");
      else                   asm volatile("s_waitcnt vmcnt(3)" ::: "memory");
    } else {
      asm volatile("s_waitcnt vmcnt(0)" ::: "memory");
    }
    __builtin_amdgcn_s_barrier();
    __builtin_amdgcn_sched_barrier(0);
    if (t + 2 < T) {
      int s2 = slot + 2; if (s2 >= 3) s2 -= 3;
      stage(t + 2, s2);
    }
    const char* pA = (const char*)As[slot];
    const char* pB = (const char*)Bs[slot];
    bf16x8 a[8], b[NF];
#pragma unroll
    for (int mi = 0; mi < 8; mi++) a[mi] = *(const bf16x8*)(pA + rdA + mi * 1024);
#pragma unroll
    for (int ni = 0; ni < NF; ni++) b[ni] = *(const bf16x8*)(pB + rdB + ni * 1024);
    asm volatile("s_waitcnt lgkmcnt(0)" ::: "memory");
    __builtin_amdgcn_sched_barrier(0);
    __builtin_amdgcn_s_setprio(1);
#pragma unroll
    for (int mi = 0; mi < 8; mi++)
#pragma unroll
      for (int ni = 0; ni < NF; ni++)
        acc[mi][ni] = MFMA_BF16(a[mi], b[ni], acc[mi][ni], 0, 0, 0);
    __builtin_amdgcn_s_setprio(0);
    slot = (slot + 1 == 3) ? 0 : slot + 1;
  }

  // ---- epilogue
  const int row_base = m0 + wm * 128;
  const int col_base = n0 + wn * 16 * NF + l15;
#pragma unroll
  for (int mi = 0; mi < 8; mi++)
#pragma unroll
    for (int ni = 0; ni < NF; ni++) {
      const int c = col_base + ni * 16;
#pragma unroll
      for (int r = 0; r < 4; r++) {
        const int row = row_base + mi * 16 + 4 * g + r;
        const size_t idx = (size_t)row * N + c;
        float v = acc[mi][ni][r];
        if constexpr (MODE == 0) {
          outb[idx] = (bf16)v;
        } else if constexpr (MODE == 1) {
          float xv = v + resid[idx];
          outf[idx] = xv;
          outb[idx] = (bf16)xv;
        } else if constexpr (MODE == 2) {
          outb[idx] = (bf16)gelu_exact(v);
        } else {
          outf[idx] = v + resid[idx];
        }
      }
    }
}

// ---------------------------------------------------------------- attention
// (unchanged: 512 thr, BQ=128, paired q-tiles, K+V^T in LDS dbuf,
//  single barrier/step, register prefetch, permuted-K QK^T)
__global__ __launch_bounds__(512, 2) void attn_fwd(const bf16* __restrict__ qkv,
                                                   bf16* __restrict__ O) {
  __shared__ __align__(16) char Kl[2][64 * 128];
  __shared__ __align__(16) char Vt[2][64 * 128];
  const int tid = threadIdx.x;
  const int lane = tid & 63, w = tid >> 6;
  const int g = lane >> 4, l15 = lane & 15;
  const int bh = blockIdx.x;
  const int bx = blockIdx.y;
  const int b = bh >> 4, hh = bh & 15;
  const size_t tokbase = (size_t)b * 2048;

  const bf16* kbase = qkv + tokbase * 3072 + 1024 + hh * 64;
  const bf16* vbase = qkv + tokbase * 3072 + 2048 + hh * 64;
  const int kperm = 8 * (l15 >> 2) + (l15 & 3);

  const bool vstage = tid < 256;
  const int t2 = tid & 255;
  const int vrg = t2 >> 4, vds = (t2 & 15) * 4;
  const int krow = t2 >> 2, ksl = t2 & 3;
  const int kswzr = (krow & 3) | ((krow & 8) >> 1);

  union U4 { ushort4 v; u16 a[4]; };
  U4 vr[4];
  uint4 kpr0, kpr1;

  auto prefetch = [&](int k0n) {
    if (vstage) {
#pragma unroll
      for (int i4 = 0; i4 < 4; i4++)
        vr[i4].v = *(const ushort4*)(vbase + (size_t)(k0n + 4 * vrg + i4) * 3072 + vds);
    } else {
      const bf16* kp = kbase + (size_t)(k0n + krow) * 3072 + 8 * ksl;
      kpr0 = *(const uint4*)(kp);
      kpr1 = *(const uint4*)(kp + 32);
    }
  };

  prefetch(0);
  int cur = 0;

  for (int half = 0; half < 2; half++) {
    const int xT = half ? (15 - bx) : bx;
    const int q0 = xT * 128;
    const int qw0 = q0 + 16 * w;
    const int qi = qw0 + l15;
    const int kend = q0 + 128;

    const bf16* qptr = qkv + (tokbase + qw0 + l15) * 3072 + hh * 64 + 8 * g;
    const bf16x8 qf0 = *(const bf16x8*)(qptr);
    const bf16x8 qf1 = *(const bf16x8*)(qptr + 32);

    f32x4 ot[4] = {};
    float m_i = -INFINITY, l_i = 0.0f;

    for (int k0 = 0; k0 < kend; k0 += 64) {
      char* Kc = Kl[cur];
      char* Vc = Vt[cur];
      if (vstage) {
#pragma unroll
        for (int dj = 0; dj < 4; dj++) {
          const int d = vds + dj;
          u32 lo = (u32)vr[0].a[dj] | ((u32)vr[1].a[dj] << 16);
          u32 hi = (u32)vr[2].a[dj] | ((u32)vr[3].a[dj] << 16);
          const int boff = d * 128 + ((((vrg >> 1) ^ ((d >> 1) & 7)) << 4)) + ((vrg & 1) << 3);
          *(uint2*)(Vc + boff) = make_uint2(lo, hi);
        }
      } else {
        *(uint4*)(Kc + krow * 128 + ((ksl ^ kswzr) << 4)) = kpr0;
        *(uint4*)(Kc + krow * 128 + (((ksl | 4) ^ kswzr) << 4)) = kpr1;
      }
      __syncthreads();

      const int k0n = (k0 + 64 < kend) ? k0 + 64 : 0;
      prefetch(k0n);

      if (k0 <= qw0 + 15) {
        const bool lastT = (k0 + 63 > qw0);
        const int npair = lastT ? (((qw0 + 15 - k0) >> 5) + 1) : 2;

        f32x4 st[4];
#pragma unroll
        for (int ip = 0; ip < 2; ip++)
          if (ip < npair) {
#pragma unroll
            for (int h2 = 0; h2 < 2; h2++) {
              const int kr = 32 * ip + 4 * h2 + kperm;
              const int swzk = (kr & 3) | ((kr & 8) >> 1);
              const char* kro = Kc + kr * 128;
              bf16x8 ka = *(const bf16x8*)(kro + ((g ^ swzk) << 4));
              bf16x8 kb = *(const bf16x8*)(kro + (((g | 4) ^ swzk) << 4));
              f32x4 z = {};
              z = MFMA_BF16(ka, qf0, z, 0, 0, 0);
              st[2 * ip + h2] = MFMA_BF16(kb, qf1, z, 0, 0, 0);
            }
          }

        float p[4][4];
        float mt = -INFINITY;
#pragma unroll
        for (int ip = 0; ip < 2; ip++)
          if (ip < npair) {
#pragma unroll
            for (int h2 = 0; h2 < 2; h2++)
#pragma unroll
              for (int r = 0; r < 4; r++) {
                const int kk = k0 + 32 * ip + 8 * g + 4 * h2 + r;
                float v = (float)st[2 * ip + h2][r] * 0.125f;
                if (lastT && kk > qi) v = -INFINITY;
                p[2 * ip + h2][r] = v;
                mt = fmaxf(mt, v);
              }
          }
        mt = fmaxf(mt, __shfl_xor(mt, 16, 64));
        mt = fmaxf(mt, __shfl_xor(mt, 32, 64));

        if (!__all(mt - m_i <= 8.0f)) {
          const float m_new = fmaxf(m_i, mt);
          const float alpha = __expf(m_i - m_new);
          l_i *= alpha;
#pragma unroll
          for (int dt = 0; dt < 4; dt++)
#pragma unroll
            for (int r = 0; r < 4; r++) ot[dt][r] *= alpha;
          m_i = m_new;
        }
        float s = 0.0f;
#pragma unroll
        for (int ip = 0; ip < 2; ip++)
          if (ip < npair) {
#pragma unroll
            for (int h2 = 0; h2 < 2; h2++)
#pragma unroll
              for (int r = 0; r < 4; r++) {
                float e = __expf(p[2 * ip + h2][r] - m_i);
                p[2 * ip + h2][r] = e;
                s += e;
              }
          }
        s += __shfl_xor(s, 16, 64);
        s += __shfl_xor(s, 32, 64);
        l_i += s;

#pragma unroll
        for (int ip = 0; ip < 2; ip++)
          if (ip < npair) {
            bf16x8 pf;
#pragma unroll
            for (int h2 = 0; h2 < 2; h2++)
#pragma unroll
              for (int r = 0; r < 4; r++) pf[4 * h2 + r] = (bf16)p[2 * ip + h2][r];
#pragma unroll
            for (int dt = 0; dt < 4; dt++) {
              const bf16x8 vf = *(const bf16x8*)(
                  Vc + (dt * 16 + l15) * 128 + (((4 * ip + g) ^ (l15 >> 1)) << 4));
              ot[dt] = MFMA_BF16(vf, pf, ot[dt], 0, 0, 0);
            }
          }
      }
      cur ^= 1;
    }

    const float inv = 1.0f / l_i;
    bf16* obase = O + (tokbase + qw0 + l15) * 1024 + hh * 64;
#pragma unroll
    for (int dt = 0; dt < 4; dt++) {
      bf16x4 ov;
#pragma unroll
      for (int r = 0; r < 4; r++) ov[r] = (bf16)(ot[dt][r] * inv);
      *(bf16x4*)(obase + dt * 16 + 4 * g) = ov;
    }
  }
}

// ---------------------------------------------------------------- launch
extern "C" void kernel_launch(void* const* d_in, const int* in_sizes, int n_in,
                              void* d_out, int out_size, void* d_ws, size_t ws_size,
                              hipStream_t stream) {
  const float* x = (const float*)d_in[0];
  const float* w_qkv = (const float*)d_in[1];
  const float* w_out = (const float*)d_in[2];
  const float* w_ff1 = (const float*)d_in[3];
  const float* w_ff2 = (const float*)d_in[4];
  float* out = (float*)d_out;

  char* ws = (char*)d_ws;
  size_t off = 0;
  auto alloc = [&](size_t bytes) {
    void* p = ws + off;
    off += (bytes + 255) & ~(size_t)255;
    return p;
  };
  const size_t M = 8192;
  bf16* X16   = (bf16*)alloc(M * 1024 * 2);
  bf16* WqkvT = (bf16*)alloc(3072ull * 1024 * 2);
  bf16* WoutT = (bf16*)alloc(1024ull * 1024 * 2);
  bf16* Wff1T = (bf16*)alloc(4096ull * 1024 * 2);
  bf16* Wff2T = (bf16*)alloc(1024ull * 4096 * 2);
  bf16* QKV   = (bf16*)alloc(M * 3072 * 2);
  bf16* Obuf  = (bf16*)alloc(M * 1024 * 2);
  float* x1   = (float*)alloc(M * 1024 * 4);
  bf16* x1b   = (bf16*)alloc(M * 1024 * 2);
  bf16* Hbuf  = (bf16*)alloc(M * 4096 * 2);

  cvt_f32_bf16<<<8192, 256, 0, stream>>>(x, X16, 8192 * 1024);
  transpose_w<<<dim3(3072 / 32, 1024 / 32), 256, 0, stream>>>(w_qkv, WqkvT, 1024, 3072);
  transpose_w<<<dim3(1024 / 32, 1024 / 32), 256, 0, stream>>>(w_out, WoutT, 1024, 1024);
  transpose_w<<<dim3(4096 / 32, 1024 / 32), 256, 0, stream>>>(w_ff1, Wff1T, 1024, 4096);
  transpose_w<<<dim3(1024 / 32, 4096 / 32), 256, 0, stream>>>(w_ff2, Wff2T, 4096, 1024);

  // grids: (M/256)*(N/(64*NF)); all multiples of 8; qkv NF=2 -> 3 exact rounds
  gemm_bt<0, 2><<<32 * 24, 512, 0, stream>>>(X16, WqkvT, QKV, nullptr, nullptr, 1024, 3072);
  attn_fwd<<<dim3(64, 8), 512, 0, stream>>>(QKV, Obuf);
  gemm_bt<1, 2><<<32 * 8, 512, 0, stream>>>(Obuf, WoutT, x1b, x1, x, 1024, 1024);
  gemm_bt<2, 4><<<32 * 16, 512, 0, stream>>>(x1b, Wff1T, Hbuf, nullptr, nullptr, 1024, 4096);
  gemm_bt<3, 2><<<32 * 8, 512, 0, stream>>>(Hbuf, Wff2T, nullptr, out, x1, 4096, 1024);
}

// Round 10
// 417.955 us; speedup vs baseline: 1.1432x; 1.1432x over previous
//
#include <hip/hip_runtime.h>

typedef __bf16 bf16;
typedef __bf16 bf16x8 __attribute__((ext_vector_type(8)));
typedef __bf16 bf16x4 __attribute__((ext_vector_type(4)));
typedef float f32x4 __attribute__((ext_vector_type(4)));
typedef unsigned int u32;
typedef unsigned short u16;

#define MFMA_BF16 __builtin_amdgcn_mfma_f32_16x16x32_bf16

#define GLOAD_LDS(g, l)                                        \
  __builtin_amdgcn_global_load_lds(                            \
      (__attribute__((address_space(1))) void*)(g),            \
      (__attribute__((address_space(3))) void*)(l), 16, 0, 0)

// ---------------------------------------------------------------- utilities
__global__ void cvt_f32_bf16(const float* __restrict__ in, bf16* __restrict__ out, int n) {
  int i = (blockIdx.x * blockDim.x + threadIdx.x) * 4;
  if (i >= n) return;
  float4 v = *(const float4*)(in + i);
  bf16x4 o;
  o[0] = (bf16)v.x; o[1] = (bf16)v.y; o[2] = (bf16)v.z; o[3] = (bf16)v.w;
  *(bf16x4*)(out + i) = o;
}

// W [K][N] fp32 -> Wt [N][K] bf16
__global__ void transpose_w(const float* __restrict__ w, bf16* __restrict__ wt, int K, int N) {
  __shared__ float tile[32][33];
  int n0 = blockIdx.x * 32, k0 = blockIdx.y * 32;
  int t = threadIdx.x;
  int c = t & 31, r = t >> 5;
#pragma unroll
  for (int i = 0; i < 4; i++)
    tile[r + i * 8][c] = w[(size_t)(k0 + r + i * 8) * N + n0 + c];
  __syncthreads();
#pragma unroll
  for (int i = 0; i < 4; i++)
    wt[(size_t)(n0 + r + i * 8) * K + k0 + c] = (bf16)tile[c][r + i * 8];
}

__device__ inline float gelu_exact(float x) {
  return 0.5f * x * (1.0f + erff(x * 0.70710678118654752f));
}

// ---------------------------------------------------------------- GEMM
// 256x128 tile, BK=32, 512 thr = 8 waves (4M x 2N), wave tile 64x64,
// acc[4][4] (64 AGPR). Double-buffered LDS 48KB -> TWO blocks/CU
// (launch_bounds(512,4)): the per-tile __syncthreads vmcnt drain of one
// block is hidden by the other block's compute (m97 mechanism).
// One barrier per K-tile (dbuf WAR-safe: tile t-1 reads are lgkm-drained
// before barrier t; stage(t+1) issues after it). LDS reads 0-conflict via
// chunk ^= (row>>1)&3 swizzle on the READ + inverse on the per-lane GLOBAL
// source (LDS dest lane-linear, gload_lds rule). XCD-chunked 1-D grid,
// M-tiles fastest.
template <int MODE>
__global__ __launch_bounds__(512, 4) void gemm_bt(
    const bf16* __restrict__ A, const bf16* __restrict__ Bt,
    bf16* __restrict__ outb, float* __restrict__ outf,
    const float* __restrict__ residf, const bf16* __restrict__ residb,
    int K, int N) {
  __shared__ __align__(16) bf16 As[2][256 * 32];
  __shared__ __align__(16) bf16 Bs[2][128 * 32];
  const int tid = threadIdx.x;
  const int lane = tid & 63, w = tid >> 6;
  const int g = lane >> 4, l15 = lane & 15;
  const int wm = w >> 1, wn = w & 1;

  const int cpx = (int)gridDim.x >> 3;
  const int widx = ((int)blockIdx.x & 7) * cpx + ((int)blockIdx.x >> 3);
  const int m0 = (widx & 31) * 256, n0 = (widx >> 5) * 128;

  f32x4 acc[4][4] = {};

  // staging: thread -> row tid>>2 (128 rows/issue), 16B chunk (tid&3),
  // chunk pre-swizzled with the inverse of the read swizzle.
  const int srow = tid >> 2;
  const int schunk = (tid & 3) ^ ((tid >> 3) & 3);
  const char* gA = (const char*)A;
  const char* gB = (const char*)Bt;
  const size_t aOff = ((size_t)(m0 + srow) * K + schunk * 8) * 2;
  const size_t bOff = ((size_t)(n0 + srow) * K + schunk * 8) * 2;

  auto stage = [&](int kt, int slot) {
    const size_t kb = (size_t)kt * 64;  // kt*32 elems * 2B
    GLOAD_LDS(gA + aOff + kb, &As[slot][(w * 16) * 32]);
    GLOAD_LDS(gA + aOff + (size_t)128 * K * 2 + kb, &As[slot][(128 + w * 16) * 32]);
    GLOAD_LDS(gB + bOff + kb, &Bs[slot][(w * 16) * 32]);
  };

  // read offsets (bytes): row*64 + swizzled 16B chunk
  const int rsw = (g ^ ((l15 >> 1) & 3)) << 4;
  const int rdA = (wm * 64 + l15) * 64 + rsw;
  const int rdB = (wn * 64 + l15) * 64 + rsw;

  const int T = K >> 5;
  stage(0, 0);

  int slot = 0;
  for (int t = 0; t < T; ++t) {
    __syncthreads();  // drains stage(t); other resident block hides this
    if (t + 1 < T) stage(t + 1, slot ^ 1);
    const char* pA = (const char*)As[slot];
    const char* pB = (const char*)Bs[slot];
    bf16x8 a[4], b[4];
#pragma unroll
    for (int mi = 0; mi < 4; mi++) a[mi] = *(const bf16x8*)(pA + rdA + mi * 1024);
#pragma unroll
    for (int ni = 0; ni < 4; ni++) b[ni] = *(const bf16x8*)(pB + rdB + ni * 1024);
    __builtin_amdgcn_s_setprio(1);
#pragma unroll
    for (int mi = 0; mi < 4; mi++)
#pragma unroll
      for (int ni = 0; ni < 4; ni++)
        acc[mi][ni] = MFMA_BF16(a[mi], b[ni], acc[mi][ni], 0, 0, 0);
    __builtin_amdgcn_s_setprio(0);
    slot ^= 1;
  }

  // ---- epilogue
  const int row_base = m0 + wm * 64;
  const int col_base = n0 + wn * 64 + l15;
#pragma unroll
  for (int mi = 0; mi < 4; mi++)
#pragma unroll
    for (int ni = 0; ni < 4; ni++) {
      const int c = col_base + ni * 16;
#pragma unroll
      for (int r = 0; r < 4; r++) {
        const int row = row_base + mi * 16 + 4 * g + r;
        const size_t idx = (size_t)row * N + c;
        float v = acc[mi][ni][r];
        if constexpr (MODE == 0) {
          outb[idx] = (bf16)v;
        } else if constexpr (MODE == 1) {
          outb[idx] = (bf16)(v + residf[idx]);
        } else if constexpr (MODE == 2) {
          outb[idx] = (bf16)gelu_exact(v);
        } else {
          outf[idx] = v + (float)residb[idx];
        }
      }
    }
}

// ---------------------------------------------------------------- attention
// 512 thr, BQ=128, paired q-tiles, K+V^T in LDS dbuf, single barrier/step,
// register prefetch, permuted-K QK^T. LAZY SOFTMAX: no per-step cross-lane
// reduces — defer-check uses lane-local max (__all makes it global); l is
// lane-partial, reduced once after the loop; shuffles only on rare rescale.
__global__ __launch_bounds__(512, 2) void attn_fwd(const bf16* __restrict__ qkv,
                                                   bf16* __restrict__ O) {
  __shared__ __align__(16) char Kl[2][64 * 128];
  __shared__ __align__(16) char Vt[2][64 * 128];
  const int tid = threadIdx.x;
  const int lane = tid & 63, w = tid >> 6;
  const int g = lane >> 4, l15 = lane & 15;
  const int bh = blockIdx.x;
  const int bx = blockIdx.y;
  const int b = bh >> 4, hh = bh & 15;
  const size_t tokbase = (size_t)b * 2048;

  const bf16* kbase = qkv + tokbase * 3072 + 1024 + hh * 64;
  const bf16* vbase = qkv + tokbase * 3072 + 2048 + hh * 64;
  const int kperm = 8 * (l15 >> 2) + (l15 & 3);

  const bool vstage = tid < 256;
  const int t2 = tid & 255;
  const int vrg = t2 >> 4, vds = (t2 & 15) * 4;
  const int krow = t2 >> 2, ksl = t2 & 3;
  const int kswzr = (krow & 3) | ((krow & 8) >> 1);

  union U4 { ushort4 v; u16 a[4]; };
  U4 vr[4];
  uint4 kpr0, kpr1;

  auto prefetch = [&](int k0n) {
    if (vstage) {
#pragma unroll
      for (int i4 = 0; i4 < 4; i4++)
        vr[i4].v = *(const ushort4*)(vbase + (size_t)(k0n + 4 * vrg + i4) * 3072 + vds);
    } else {
      const bf16* kp = kbase + (size_t)(k0n + krow) * 3072 + 8 * ksl;
      kpr0 = *(const uint4*)(kp);
      kpr1 = *(const uint4*)(kp + 32);
    }
  };

  prefetch(0);
  int cur = 0;

  for (int half = 0; half < 2; half++) {
    const int xT = half ? (15 - bx) : bx;
    const int q0 = xT * 128;
    const int qw0 = q0 + 16 * w;
    const int qi = qw0 + l15;
    const int kend = q0 + 128;

    const bf16* qptr = qkv + (tokbase + qw0 + l15) * 3072 + hh * 64 + 8 * g;
    const bf16x8 qf0 = *(const bf16x8*)(qptr);
    const bf16x8 qf1 = *(const bf16x8*)(qptr + 32);

    f32x4 ot[4] = {};
    float m_i = -INFINITY, l_i = 0.0f;

    for (int k0 = 0; k0 < kend; k0 += 64) {
      char* Kc = Kl[cur];
      char* Vc = Vt[cur];
      if (vstage) {
#pragma unroll
        for (int dj = 0; dj < 4; dj++) {
          const int d = vds + dj;
          u32 lo = (u32)vr[0].a[dj] | ((u32)vr[1].a[dj] << 16);
          u32 hi = (u32)vr[2].a[dj] | ((u32)vr[3].a[dj] << 16);
          const int boff = d * 128 + ((((vrg >> 1) ^ ((d >> 1) & 7)) << 4)) + ((vrg & 1) << 3);
          *(uint2*)(Vc + boff) = make_uint2(lo, hi);
        }
      } else {
        *(uint4*)(Kc + krow * 128 + ((ksl ^ kswzr) << 4)) = kpr0;
        *(uint4*)(Kc + krow * 128 + (((ksl | 4) ^ kswzr) << 4)) = kpr1;
      }
      __syncthreads();

      const int k0n = (k0 + 64 < kend) ? k0 + 64 : 0;
      prefetch(k0n);

      if (k0 <= qw0 + 15) {
        const bool lastT = (k0 + 63 > qw0);
        const int npair = lastT ? (((qw0 + 15 - k0) >> 5) + 1) : 2;

        f32x4 st[4];
#pragma unroll
        for (int ip = 0; ip < 2; ip++)
          if (ip < npair) {
#pragma unroll
            for (int h2 = 0; h2 < 2; h2++) {
              const int kr = 32 * ip + 4 * h2 + kperm;
              const int swzk = (kr & 3) | ((kr & 8) >> 1);
              const char* kro = Kc + kr * 128;
              bf16x8 ka = *(const bf16x8*)(kro + ((g ^ swzk) << 4));
              bf16x8 kb = *(const bf16x8*)(kro + (((g | 4) ^ swzk) << 4));
              f32x4 z = {};
              z = MFMA_BF16(ka, qf0, z, 0, 0, 0);
              st[2 * ip + h2] = MFMA_BF16(kb, qf1, z, 0, 0, 0);
            }
          }

        float p[4][4];
        float mt = -INFINITY;
#pragma unroll
        for (int ip = 0; ip < 2; ip++)
          if (ip < npair) {
#pragma unroll
            for (int h2 = 0; h2 < 2; h2++)
#pragma unroll
              for (int r = 0; r < 4; r++) {
                const int kk = k0 + 32 * ip + 8 * g + 4 * h2 + r;
                float v = (float)st[2 * ip + h2][r] * 0.125f;
                if (lastT && kk > qi) v = -INFINITY;
                p[2 * ip + h2][r] = v;
                mt = fmaxf(mt, v);
              }
          }

        // lazy defer-max: lane-local mt; __all gives the wave-global answer
        if (!__all(mt - m_i <= 8.0f)) {
          mt = fmaxf(mt, __shfl_xor(mt, 16, 64));
          mt = fmaxf(mt, __shfl_xor(mt, 32, 64));
          const float m_new = fmaxf(m_i, mt);
          const float alpha = __expf(m_i - m_new);
          l_i *= alpha;
#pragma unroll
          for (int dt = 0; dt < 4; dt++)
#pragma unroll
            for (int r = 0; r < 4; r++) ot[dt][r] *= alpha;
          m_i = m_new;
        }
        float s = 0.0f;
#pragma unroll
        for (int ip = 0; ip < 2; ip++)
          if (ip < npair) {
#pragma unroll
            for (int h2 = 0; h2 < 2; h2++)
#pragma unroll
              for (int r = 0; r < 4; r++) {
                float e = __expf(p[2 * ip + h2][r] - m_i);
                p[2 * ip + h2][r] = e;
                s += e;
              }
          }
        l_i += s;  // lane-partial; reduced after the loop

#pragma unroll
        for (int ip = 0; ip < 2; ip++)
          if (ip < npair) {
            bf16x8 pf;
#pragma unroll
            for (int h2 = 0; h2 < 2; h2++)
#pragma unroll
              for (int r = 0; r < 4; r++) pf[4 * h2 + r] = (bf16)p[2 * ip + h2][r];
#pragma unroll
            for (int dt = 0; dt < 4; dt++) {
              const bf16x8 vf = *(const bf16x8*)(
                  Vc + (dt * 16 + l15) * 128 + (((4 * ip + g) ^ (l15 >> 1)) << 4));
              ot[dt] = MFMA_BF16(vf, pf, ot[dt], 0, 0, 0);
            }
          }
      }
      cur ^= 1;
    }

    l_i += __shfl_xor(l_i, 16, 64);
    l_i += __shfl_xor(l_i, 32, 64);
    const float inv = 1.0f / l_i;
    bf16* obase = O + (tokbase + qw0 + l15) * 1024 + hh * 64;
#pragma unroll
    for (int dt = 0; dt < 4; dt++) {
      bf16x4 ov;
#pragma unroll
      for (int r = 0; r < 4; r++) ov[r] = (bf16)(ot[dt][r] * inv);
      *(bf16x4*)(obase + dt * 16 + 4 * g) = ov;
    }
  }
}

// ---------------------------------------------------------------- launch
extern "C" void kernel_launch(void* const* d_in, const int* in_sizes, int n_in,
                              void* d_out, int out_size, void* d_ws, size_t ws_size,
                              hipStream_t stream) {
  const float* x = (const float*)d_in[0];
  const float* w_qkv = (const float*)d_in[1];
  const float* w_out = (const float*)d_in[2];
  const float* w_ff1 = (const float*)d_in[3];
  const float* w_ff2 = (const float*)d_in[4];
  float* out = (float*)d_out;

  char* ws = (char*)d_ws;
  size_t off = 0;
  auto alloc = [&](size_t bytes) {
    void* p = ws + off;
    off += (bytes + 255) & ~(size_t)255;
    return p;
  };
  const size_t M = 8192;
  bf16* X16   = (bf16*)alloc(M * 1024 * 2);
  bf16* WqkvT = (bf16*)alloc(3072ull * 1024 * 2);
  bf16* WoutT = (bf16*)alloc(1024ull * 1024 * 2);
  bf16* Wff1T = (bf16*)alloc(4096ull * 1024 * 2);
  bf16* Wff2T = (bf16*)alloc(1024ull * 4096 * 2);
  bf16* QKV   = (bf16*)alloc(M * 3072 * 2);
  bf16* Obuf  = (bf16*)alloc(M * 1024 * 2);
  bf16* x1b   = (bf16*)alloc(M * 1024 * 2);
  bf16* Hbuf  = (bf16*)alloc(M * 4096 * 2);

  cvt_f32_bf16<<<8192, 256, 0, stream>>>(x, X16, 8192 * 1024);
  transpose_w<<<dim3(3072 / 32, 1024 / 32), 256, 0, stream>>>(w_qkv, WqkvT, 1024, 3072);
  transpose_w<<<dim3(1024 / 32, 1024 / 32), 256, 0, stream>>>(w_out, WoutT, 1024, 1024);
  transpose_w<<<dim3(4096 / 32, 1024 / 32), 256, 0, stream>>>(w_ff1, Wff1T, 1024, 4096);
  transpose_w<<<dim3(1024 / 32, 4096 / 32), 256, 0, stream>>>(w_ff2, Wff2T, 4096, 1024);

  // grids: (N/128)*(M/256), 1-D, XCD-chunked (all multiples of 8)
  gemm_bt<0><<<24 * 32, 512, 0, stream>>>(X16, WqkvT, QKV, nullptr, nullptr, nullptr, 1024, 3072);
  attn_fwd<<<dim3(64, 8), 512, 0, stream>>>(QKV, Obuf);
  gemm_bt<1><<<8 * 32, 512, 0, stream>>>(Obuf, WoutT, x1b, nullptr, x, nullptr, 1024, 1024);
  gemm_bt<2><<<32 * 32, 512, 0, stream>>>(x1b, Wff1T, Hbuf, nullptr, nullptr, nullptr, 1024, 4096);
  gemm_bt<3><<<8 * 32, 512, 0, stream>>>(Hbuf, Wff2T, nullptr, out, nullptr, x1b, 4096, 1024);
}

// Round 11
// 386.796 us; speedup vs baseline: 1.2353x; 1.0806x over previous
//
#include <hip/hip_runtime.h>

typedef __bf16 bf16;
typedef __bf16 bf16x8 __attribute__((ext_vector_type(8)));
typedef __bf16 bf16x4 __attribute__((ext_vector_type(4)));
typedef float f32x4 __attribute__((ext_vector_type(4)));
typedef unsigned int u32;
typedef unsigned short u16;

#define MFMA_BF16 __builtin_amdgcn_mfma_f32_16x16x32_bf16

#define GLOAD_LDS(g, l)                                        \
  __builtin_amdgcn_global_load_lds(                            \
      (__attribute__((address_space(1))) void*)(g),            \
      (__attribute__((address_space(3))) void*)(l), 16, 0, 0)

// ---------------------------------------------------------------- utilities
__global__ void cvt_f32_bf16(const float* __restrict__ in, bf16* __restrict__ out, int n) {
  int i = (blockIdx.x * blockDim.x + threadIdx.x) * 4;
  if (i >= n) return;
  float4 v = *(const float4*)(in + i);
  bf16x4 o;
  o[0] = (bf16)v.x; o[1] = (bf16)v.y; o[2] = (bf16)v.z; o[3] = (bf16)v.w;
  *(bf16x4*)(out + i) = o;
}

// W [K][N] fp32 -> Wt [N][K] bf16
__global__ void transpose_w(const float* __restrict__ w, bf16* __restrict__ wt, int K, int N) {
  __shared__ float tile[32][33];
  int n0 = blockIdx.x * 32, k0 = blockIdx.y * 32;
  int t = threadIdx.x;
  int c = t & 31, r = t >> 5;
#pragma unroll
  for (int i = 0; i < 4; i++)
    tile[r + i * 8][c] = w[(size_t)(k0 + r + i * 8) * N + n0 + c];
  __syncthreads();
#pragma unroll
  for (int i = 0; i < 4; i++)
    wt[(size_t)(n0 + r + i * 8) * K + k0 + c] = (bf16)tile[c][r + i * 8];
}

__device__ inline float gelu_exact(float x) {
  return 0.5f * x * (1.0f + erff(x * 0.70710678118654752f));
}

// ---------------------------------------------------------------- GEMM
// 256x128 tile, BK=32, 512 thr = 8 waves (4M x 2N), wave tile 64x64,
// acc[4][4]. Dbuf LDS 48KB, 2 blocks/CU, one barrier/K-tile (R10 structure,
// unchanged). NEW: supertile L2 ordering — within each XCD chunk, blocks
// walk 4Mx4N supertiles (A 2MB + B 1MB <= 4MB L2), N-supertiles fastest
// inside a fixed M-supergroup. Chunk arithmetic makes XCD x own exactly
// M-rows [x*1024*4, +1024): A fetched ONCE chip-wide, B once per XCD.
template <int MODE>
__global__ __launch_bounds__(512, 4) void gemm_bt(
    const bf16* __restrict__ A, const bf16* __restrict__ Bt,
    bf16* __restrict__ outb, float* __restrict__ outf,
    const float* __restrict__ residf, const bf16* __restrict__ residb,
    int K, int N) {
  __shared__ __align__(16) bf16 As[2][256 * 32];
  __shared__ __align__(16) bf16 Bs[2][128 * 32];
  const int tid = threadIdx.x;
  const int lane = tid & 63, w = tid >> 6;
  const int g = lane >> 4, l15 = lane & 15;
  const int wm = w >> 1, wn = w & 1;

  // ---- XCD chunk + supertile decode (M/256 == 32 tiles always)
  const int NT = N >> 7;                    // N-tiles of 128
  const int nsup = NT >> 2;                 // N-supertiles (4 tiles each)
  const int cpx = (int)gridDim.x >> 3;
  const int widx = ((int)blockIdx.x & 7) * cpx + ((int)blockIdx.x >> 3);
  const int s = widx >> 4, r4 = widx & 15;  // supertile id, 4x4 inner (m fastest)
  const int sm = s / nsup, sn = s - sm * nsup;
  const int m0 = (sm * 4 + (r4 & 3)) * 256;
  const int n0 = (sn * 4 + (r4 >> 2)) * 128;

  f32x4 acc[4][4] = {};

  // staging: thread -> row tid>>2 (128 rows/issue), 16B chunk (tid&3),
  // chunk pre-swizzled with the inverse of the read swizzle.
  const int srow = tid >> 2;
  const int schunk = (tid & 3) ^ ((tid >> 3) & 3);
  const char* gA = (const char*)A;
  const char* gB = (const char*)Bt;
  const size_t aOff = ((size_t)(m0 + srow) * K + schunk * 8) * 2;
  const size_t bOff = ((size_t)(n0 + srow) * K + schunk * 8) * 2;

  auto stage = [&](int kt, int slot) {
    const size_t kb = (size_t)kt * 64;  // kt*32 elems * 2B
    GLOAD_LDS(gA + aOff + kb, &As[slot][(w * 16) * 32]);
    GLOAD_LDS(gA + aOff + (size_t)128 * K * 2 + kb, &As[slot][(128 + w * 16) * 32]);
    GLOAD_LDS(gB + bOff + kb, &Bs[slot][(w * 16) * 32]);
  };

  // read offsets (bytes): row*64 + swizzled 16B chunk
  const int rsw = (g ^ ((l15 >> 1) & 3)) << 4;
  const int rdA = (wm * 64 + l15) * 64 + rsw;
  const int rdB = (wn * 64 + l15) * 64 + rsw;

  const int T = K >> 5;
  stage(0, 0);

  int slot = 0;
  for (int t = 0; t < T; ++t) {
    __syncthreads();  // drains stage(t); paired resident block hides this
    if (t + 1 < T) stage(t + 1, slot ^ 1);
    const char* pA = (const char*)As[slot];
    const char* pB = (const char*)Bs[slot];
    bf16x8 a[4], b[4];
#pragma unroll
    for (int mi = 0; mi < 4; mi++) a[mi] = *(const bf16x8*)(pA + rdA + mi * 1024);
#pragma unroll
    for (int ni = 0; ni < 4; ni++) b[ni] = *(const bf16x8*)(pB + rdB + ni * 1024);
    __builtin_amdgcn_s_setprio(1);
#pragma unroll
    for (int mi = 0; mi < 4; mi++)
#pragma unroll
      for (int ni = 0; ni < 4; ni++)
        acc[mi][ni] = MFMA_BF16(a[mi], b[ni], acc[mi][ni], 0, 0, 0);
    __builtin_amdgcn_s_setprio(0);
    slot ^= 1;
  }

  // ---- epilogue
  const int row_base = m0 + wm * 64;
  const int col_base = n0 + wn * 64 + l15;
#pragma unroll
  for (int mi = 0; mi < 4; mi++)
#pragma unroll
    for (int ni = 0; ni < 4; ni++) {
      const int c = col_base + ni * 16;
#pragma unroll
      for (int r = 0; r < 4; r++) {
        const int row = row_base + mi * 16 + 4 * g + r;
        const size_t idx = (size_t)row * N + c;
        float v = acc[mi][ni][r];
        if constexpr (MODE == 0) {
          outb[idx] = (bf16)v;
        } else if constexpr (MODE == 1) {
          outb[idx] = (bf16)(v + residf[idx]);
        } else if constexpr (MODE == 2) {
          outb[idx] = (bf16)gelu_exact(v);
        } else {
          outf[idx] = v + (float)residb[idx];
        }
      }
    }
}

// ---------------------------------------------------------------- attention
// (unchanged from R10: 512 thr, BQ=128, paired q-tiles, K+V^T LDS dbuf,
//  single barrier/step, register prefetch, permuted-K QK^T, lazy softmax)
__global__ __launch_bounds__(512, 2) void attn_fwd(const bf16* __restrict__ qkv,
                                                   bf16* __restrict__ O) {
  __shared__ __align__(16) char Kl[2][64 * 128];
  __shared__ __align__(16) char Vt[2][64 * 128];
  const int tid = threadIdx.x;
  const int lane = tid & 63, w = tid >> 6;
  const int g = lane >> 4, l15 = lane & 15;
  const int bh = blockIdx.x;
  const int bx = blockIdx.y;
  const int b = bh >> 4, hh = bh & 15;
  const size_t tokbase = (size_t)b * 2048;

  const bf16* kbase = qkv + tokbase * 3072 + 1024 + hh * 64;
  const bf16* vbase = qkv + tokbase * 3072 + 2048 + hh * 64;
  const int kperm = 8 * (l15 >> 2) + (l15 & 3);

  const bool vstage = tid < 256;
  const int t2 = tid & 255;
  const int vrg = t2 >> 4, vds = (t2 & 15) * 4;
  const int krow = t2 >> 2, ksl = t2 & 3;
  const int kswzr = (krow & 3) | ((krow & 8) >> 1);

  union U4 { ushort4 v; u16 a[4]; };
  U4 vr[4];
  uint4 kpr0, kpr1;

  auto prefetch = [&](int k0n) {
    if (vstage) {
#pragma unroll
      for (int i4 = 0; i4 < 4; i4++)
        vr[i4].v = *(const ushort4*)(vbase + (size_t)(k0n + 4 * vrg + i4) * 3072 + vds);
    } else {
      const bf16* kp = kbase + (size_t)(k0n + krow) * 3072 + 8 * ksl;
      kpr0 = *(const uint4*)(kp);
      kpr1 = *(const uint4*)(kp + 32);
    }
  };

  prefetch(0);
  int cur = 0;

  for (int half = 0; half < 2; half++) {
    const int xT = half ? (15 - bx) : bx;
    const int q0 = xT * 128;
    const int qw0 = q0 + 16 * w;
    const int qi = qw0 + l15;
    const int kend = q0 + 128;

    const bf16* qptr = qkv + (tokbase + qw0 + l15) * 3072 + hh * 64 + 8 * g;
    const bf16x8 qf0 = *(const bf16x8*)(qptr);
    const bf16x8 qf1 = *(const bf16x8*)(qptr + 32);

    f32x4 ot[4] = {};
    float m_i = -INFINITY, l_i = 0.0f;

    for (int k0 = 0; k0 < kend; k0 += 64) {
      char* Kc = Kl[cur];
      char* Vc = Vt[cur];
      if (vstage) {
#pragma unroll
        for (int dj = 0; dj < 4; dj++) {
          const int d = vds + dj;
          u32 lo = (u32)vr[0].a[dj] | ((u32)vr[1].a[dj] << 16);
          u32 hi = (u32)vr[2].a[dj] | ((u32)vr[3].a[dj] << 16);
          const int boff = d * 128 + ((((vrg >> 1) ^ ((d >> 1) & 7)) << 4)) + ((vrg & 1) << 3);
          *(uint2*)(Vc + boff) = make_uint2(lo, hi);
        }
      } else {
        *(uint4*)(Kc + krow * 128 + ((ksl ^ kswzr) << 4)) = kpr0;
        *(uint4*)(Kc + krow * 128 + (((ksl | 4) ^ kswzr) << 4)) = kpr1;
      }
      __syncthreads();

      const int k0n = (k0 + 64 < kend) ? k0 + 64 : 0;
      prefetch(k0n);

      if (k0 <= qw0 + 15) {
        const bool lastT = (k0 + 63 > qw0);
        const int npair = lastT ? (((qw0 + 15 - k0) >> 5) + 1) : 2;

        f32x4 st[4];
#pragma unroll
        for (int ip = 0; ip < 2; ip++)
          if (ip < npair) {
#pragma unroll
            for (int h2 = 0; h2 < 2; h2++) {
              const int kr = 32 * ip + 4 * h2 + kperm;
              const int swzk = (kr & 3) | ((kr & 8) >> 1);
              const char* kro = Kc + kr * 128;
              bf16x8 ka = *(const bf16x8*)(kro + ((g ^ swzk) << 4));
              bf16x8 kb = *(const bf16x8*)(kro + (((g | 4) ^ swzk) << 4));
              f32x4 z = {};
              z = MFMA_BF16(ka, qf0, z, 0, 0, 0);
              st[2 * ip + h2] = MFMA_BF16(kb, qf1, z, 0, 0, 0);
            }
          }

        float p[4][4];
        float mt = -INFINITY;
#pragma unroll
        for (int ip = 0; ip < 2; ip++)
          if (ip < npair) {
#pragma unroll
            for (int h2 = 0; h2 < 2; h2++)
#pragma unroll
              for (int r = 0; r < 4; r++) {
                const int kk = k0 + 32 * ip + 8 * g + 4 * h2 + r;
                float v = (float)st[2 * ip + h2][r] * 0.125f;
                if (lastT && kk > qi) v = -INFINITY;
                p[2 * ip + h2][r] = v;
                mt = fmaxf(mt, v);
              }
          }

        if (!__all(mt - m_i <= 8.0f)) {
          mt = fmaxf(mt, __shfl_xor(mt, 16, 64));
          mt = fmaxf(mt, __shfl_xor(mt, 32, 64));
          const float m_new = fmaxf(m_i, mt);
          const float alpha = __expf(m_i - m_new);
          l_i *= alpha;
#pragma unroll
          for (int dt = 0; dt < 4; dt++)
#pragma unroll
            for (int r = 0; r < 4; r++) ot[dt][r] *= alpha;
          m_i = m_new;
        }
        float s = 0.0f;
#pragma unroll
        for (int ip = 0; ip < 2; ip++)
          if (ip < npair) {
#pragma unroll
            for (int h2 = 0; h2 < 2; h2++)
#pragma unroll
              for (int r = 0; r < 4; r++) {
                float e = __expf(p[2 * ip + h2][r] - m_i);
                p[2 * ip + h2][r] = e;
                s += e;
              }
          }
        l_i += s;

#pragma unroll
        for (int ip = 0; ip < 2; ip++)
          if (ip < npair) {
            bf16x8 pf;
#pragma unroll
            for (int h2 = 0; h2 < 2; h2++)
#pragma unroll
              for (int r = 0; r < 4; r++) pf[4 * h2 + r] = (bf16)p[2 * ip + h2][r];
#pragma unroll
            for (int dt = 0; dt < 4; dt++) {
              const bf16x8 vf = *(const bf16x8*)(
                  Vc + (dt * 16 + l15) * 128 + (((4 * ip + g) ^ (l15 >> 1)) << 4));
              ot[dt] = MFMA_BF16(vf, pf, ot[dt], 0, 0, 0);
            }
          }
      }
      cur ^= 1;
    }

    l_i += __shfl_xor(l_i, 16, 64);
    l_i += __shfl_xor(l_i, 32, 64);
    const float inv = 1.0f / l_i;
    bf16* obase = O + (tokbase + qw0 + l15) * 1024 + hh * 64;
#pragma unroll
    for (int dt = 0; dt < 4; dt++) {
      bf16x4 ov;
#pragma unroll
      for (int r = 0; r < 4; r++) ov[r] = (bf16)(ot[dt][r] * inv);
      *(bf16x4*)(obase + dt * 16 + 4 * g) = ov;
    }
  }
}

// ---------------------------------------------------------------- launch
extern "C" void kernel_launch(void* const* d_in, const int* in_sizes, int n_in,
                              void* d_out, int out_size, void* d_ws, size_t ws_size,
                              hipStream_t stream) {
  const float* x = (const float*)d_in[0];
  const float* w_qkv = (const float*)d_in[1];
  const float* w_out = (const float*)d_in[2];
  const float* w_ff1 = (const float*)d_in[3];
  const float* w_ff2 = (const float*)d_in[4];
  float* out = (float*)d_out;

  char* ws = (char*)d_ws;
  size_t off = 0;
  auto alloc = [&](size_t bytes) {
    void* p = ws + off;
    off += (bytes + 255) & ~(size_t)255;
    return p;
  };
  const size_t M = 8192;
  bf16* X16   = (bf16*)alloc(M * 1024 * 2);
  bf16* WqkvT = (bf16*)alloc(3072ull * 1024 * 2);
  bf16* WoutT = (bf16*)alloc(1024ull * 1024 * 2);
  bf16* Wff1T = (bf16*)alloc(4096ull * 1024 * 2);
  bf16* Wff2T = (bf16*)alloc(1024ull * 4096 * 2);
  bf16* QKV   = (bf16*)alloc(M * 3072 * 2);
  bf16* Obuf  = (bf16*)alloc(M * 1024 * 2);
  bf16* x1b   = (bf16*)alloc(M * 1024 * 2);
  bf16* Hbuf  = (bf16*)alloc(M * 4096 * 2);

  cvt_f32_bf16<<<8192, 256, 0, stream>>>(x, X16, 8192 * 1024);
  transpose_w<<<dim3(3072 / 32, 1024 / 32), 256, 0, stream>>>(w_qkv, WqkvT, 1024, 3072);
  transpose_w<<<dim3(1024 / 32, 1024 / 32), 256, 0, stream>>>(w_out, WoutT, 1024, 1024);
  transpose_w<<<dim3(4096 / 32, 1024 / 32), 256, 0, stream>>>(w_ff1, Wff1T, 1024, 4096);
  transpose_w<<<dim3(1024 / 32, 4096 / 32), 256, 0, stream>>>(w_ff2, Wff2T, 4096, 1024);

  // grids: (N/128)*(M/256), 1-D, XCD-chunked + supertile order
  gemm_bt<0><<<24 * 32, 512, 0, stream>>>(X16, WqkvT, QKV, nullptr, nullptr, nullptr, 1024, 3072);
  attn_fwd<<<dim3(64, 8), 512, 0, stream>>>(QKV, Obuf);
  gemm_bt<1><<<8 * 32, 512, 0, stream>>>(Obuf, WoutT, x1b, nullptr, x, nullptr, 1024, 1024);
  gemm_bt<2><<<32 * 32, 512, 0, stream>>>(x1b, Wff1T, Hbuf, nullptr, nullptr, nullptr, 1024, 4096);
  gemm_bt<3><<<8 * 32, 512, 0, stream>>>(Hbuf, Wff2T, nullptr, out, nullptr, x1b, 4096, 1024);
}

// Round 12
// 383.412 us; speedup vs baseline: 1.2462x; 1.0088x over previous
//
#include <hip/hip_runtime.h>

typedef __bf16 bf16;
typedef __bf16 bf16x8 __attribute__((ext_vector_type(8)));
typedef __bf16 bf16x4 __attribute__((ext_vector_type(4)));
typedef float f32x4 __attribute__((ext_vector_type(4)));
typedef unsigned int u32;
typedef unsigned short u16;

#define MFMA_BF16 __builtin_amdgcn_mfma_f32_16x16x32_bf16

#define GLOAD_LDS(g, l)                                        \
  __builtin_amdgcn_global_load_lds(                            \
      (__attribute__((address_space(1))) void*)(g),            \
      (__attribute__((address_space(3))) void*)(l), 16, 0, 0)

// ---------------------------------------------------------------- utilities
__global__ void cvt_f32_bf16(const float* __restrict__ in, bf16* __restrict__ out, int n) {
  int i = (blockIdx.x * blockDim.x + threadIdx.x) * 4;
  if (i >= n) return;
  float4 v = *(const float4*)(in + i);
  bf16x4 o;
  o[0] = (bf16)v.x; o[1] = (bf16)v.y; o[2] = (bf16)v.z; o[3] = (bf16)v.w;
  *(bf16x4*)(out + i) = o;
}

// W [K][N] fp32 -> Wt [N][K] bf16
__global__ void transpose_w(const float* __restrict__ w, bf16* __restrict__ wt, int K, int N) {
  __shared__ float tile[32][33];
  int n0 = blockIdx.x * 32, k0 = blockIdx.y * 32;
  int t = threadIdx.x;
  int c = t & 31, r = t >> 5;
#pragma unroll
  for (int i = 0; i < 4; i++)
    tile[r + i * 8][c] = w[(size_t)(k0 + r + i * 8) * N + n0 + c];
  __syncthreads();
#pragma unroll
  for (int i = 0; i < 4; i++)
    wt[(size_t)(n0 + r + i * 8) * K + k0 + c] = (bf16)tile[c][r + i * 8];
}

__device__ inline float gelu_exact(float x) {
  return 0.5f * x * (1.0f + erff(x * 0.70710678118654752f));
}

// ---------------------------------------------------------------- GEMM
// BM x 128 tile (BM = 2*WTM), BK=32, 256 thr = 4 waves (2M x 2N), wave
// tile WTM x 64. WTM=128: acc[8][4], 2 waves/SIMD, 48KB LDS, 2 blocks/CU.
// WTM=64: acc[4][4], 4 waves/SIMD, 32KB LDS, 2+ blocks/CU (fixes proj/ff2
// which previously ran 1 block/CU with no pairing). Rationale: R11 counters
// put the 64x64-wave-tile structure at ~90% of the LDS-BW ceiling
// (24 FLOP/LDS-byte); the 128x64 wave tile raises fragment reuse to
// ~29 FLOP/B. Schedule (single barrier/K-tile, dbuf, stage-after-barrier),
// 0-conflict swizzle, and supertile L2 ordering are unchanged from R11.
template <int MODE, int WTM>
__global__ __launch_bounds__(256, (WTM == 128) ? 2 : 4) void gemm_bt(
    const bf16* __restrict__ A, const bf16* __restrict__ Bt,
    bf16* __restrict__ outb, float* __restrict__ outf,
    const float* __restrict__ residf, const bf16* __restrict__ residb,
    int K, int N) {
  constexpr int BM = WTM * 2;
  constexpr int MR = WTM / 16;
  __shared__ __align__(16) bf16 As[2][BM * 32];
  __shared__ __align__(16) bf16 Bs[2][128 * 32];
  const int tid = threadIdx.x;
  const int lane = tid & 63, w = tid >> 6;
  const int g = lane >> 4, l15 = lane & 15;
  const int wm = w >> 1, wn = w & 1;

  // ---- XCD chunk + supertile decode (4M x 4N tile supertiles, m fastest)
  constexpr int MT = 8192 / BM;
  const int NT = N >> 7;
  const int nsupN = NT >> 2;
  const int cpx = (int)gridDim.x >> 3;
  const int widx = ((int)blockIdx.x & 7) * cpx + ((int)blockIdx.x >> 3);
  const int s = widx >> 4, r4 = widx & 15;
  const int sm = s / nsupN, sn = s - sm * nsupN;
  const int m0 = (sm * 4 + (r4 & 3)) * BM;
  const int n0 = (sn * 4 + (r4 >> 2)) * 128;

  f32x4 acc[MR][4] = {};

  // staging: thread -> row tid>>2 (64 rows/issue), 16B chunk (tid&3),
  // chunk pre-swizzled with the inverse of the read swizzle.
  const int srow = tid >> 2;
  const int schunk = (tid & 3) ^ ((tid >> 3) & 3);
  const char* gA = (const char*)A;
  const char* gB = (const char*)Bt;
  const size_t aOff = ((size_t)(m0 + srow) * K + schunk * 8) * 2;
  const size_t bOff = ((size_t)(n0 + srow) * K + schunk * 8) * 2;

  auto stage = [&](int kt, int slot) {
    const size_t kb = (size_t)kt * 64;  // kt*32 elems * 2B
#pragma unroll
    for (int i = 0; i < BM / 64; i++)
      GLOAD_LDS(gA + aOff + (size_t)(i * 64) * K * 2 + kb,
                &As[slot][(i * 64 + w * 16) * 32]);
#pragma unroll
    for (int i = 0; i < 2; i++)
      GLOAD_LDS(gB + bOff + (size_t)(i * 64) * K * 2 + kb,
                &Bs[slot][(i * 64 + w * 16) * 32]);
  };

  // read offsets (bytes): row*64 + swizzled 16B chunk
  const int rsw = (g ^ ((l15 >> 1) & 3)) << 4;
  const int rdA = (wm * WTM + l15) * 64 + rsw;
  const int rdB = (wn * 64 + l15) * 64 + rsw;

  const int T = K >> 5;
  stage(0, 0);

  int slot = 0;
  for (int t = 0; t < T; ++t) {
    __syncthreads();  // drains stage(t); paired resident block hides this
    if (t + 1 < T) stage(t + 1, slot ^ 1);
    const char* pA = (const char*)As[slot];
    const char* pB = (const char*)Bs[slot];
    bf16x8 a[MR], b[4];
#pragma unroll
    for (int mi = 0; mi < MR; mi++) a[mi] = *(const bf16x8*)(pA + rdA + mi * 1024);
#pragma unroll
    for (int ni = 0; ni < 4; ni++) b[ni] = *(const bf16x8*)(pB + rdB + ni * 1024);
    __builtin_amdgcn_s_setprio(1);
#pragma unroll
    for (int mi = 0; mi < MR; mi++)
#pragma unroll
      for (int ni = 0; ni < 4; ni++)
        acc[mi][ni] = MFMA_BF16(a[mi], b[ni], acc[mi][ni], 0, 0, 0);
    __builtin_amdgcn_s_setprio(0);
    slot ^= 1;
  }

  // ---- epilogue
  const int row_base = m0 + wm * WTM;
  const int col_base = n0 + wn * 64 + l15;
#pragma unroll
  for (int mi = 0; mi < MR; mi++)
#pragma unroll
    for (int ni = 0; ni < 4; ni++) {
      const int c = col_base + ni * 16;
#pragma unroll
      for (int r = 0; r < 4; r++) {
        const int row = row_base + mi * 16 + 4 * g + r;
        const size_t idx = (size_t)row * N + c;
        float v = acc[mi][ni][r];
        if constexpr (MODE == 0) {
          outb[idx] = (bf16)v;
        } else if constexpr (MODE == 1) {
          outb[idx] = (bf16)(v + residf[idx]);
        } else if constexpr (MODE == 2) {
          outb[idx] = (bf16)gelu_exact(v);
        } else {
          outf[idx] = v + (float)residb[idx];
        }
      }
    }
}

// ---------------------------------------------------------------- attention
// (unchanged from R11: 512 thr, BQ=128, paired q-tiles, K+V^T LDS dbuf,
//  single barrier/step, register prefetch, permuted-K QK^T, lazy softmax)
__global__ __launch_bounds__(512, 2) void attn_fwd(const bf16* __restrict__ qkv,
                                                   bf16* __restrict__ O) {
  __shared__ __align__(16) char Kl[2][64 * 128];
  __shared__ __align__(16) char Vt[2][64 * 128];
  const int tid = threadIdx.x;
  const int lane = tid & 63, w = tid >> 6;
  const int g = lane >> 4, l15 = lane & 15;
  const int bh = blockIdx.x;
  const int bx = blockIdx.y;
  const int b = bh >> 4, hh = bh & 15;
  const size_t tokbase = (size_t)b * 2048;

  const bf16* kbase = qkv + tokbase * 3072 + 1024 + hh * 64;
  const bf16* vbase = qkv + tokbase * 3072 + 2048 + hh * 64;
  const int kperm = 8 * (l15 >> 2) + (l15 & 3);

  const bool vstage = tid < 256;
  const int t2 = tid & 255;
  const int vrg = t2 >> 4, vds = (t2 & 15) * 4;
  const int krow = t2 >> 2, ksl = t2 & 3;
  const int kswzr = (krow & 3) | ((krow & 8) >> 1);

  union U4 { ushort4 v; u16 a[4]; };
  U4 vr[4];
  uint4 kpr0, kpr1;

  auto prefetch = [&](int k0n) {
    if (vstage) {
#pragma unroll
      for (int i4 = 0; i4 < 4; i4++)
        vr[i4].v = *(const ushort4*)(vbase + (size_t)(k0n + 4 * vrg + i4) * 3072 + vds);
    } else {
      const bf16* kp = kbase + (size_t)(k0n + krow) * 3072 + 8 * ksl;
      kpr0 = *(const uint4*)(kp);
      kpr1 = *(const uint4*)(kp + 32);
    }
  };

  prefetch(0);
  int cur = 0;

  for (int half = 0; half < 2; half++) {
    const int xT = half ? (15 - bx) : bx;
    const int q0 = xT * 128;
    const int qw0 = q0 + 16 * w;
    const int qi = qw0 + l15;
    const int kend = q0 + 128;

    const bf16* qptr = qkv + (tokbase + qw0 + l15) * 3072 + hh * 64 + 8 * g;
    const bf16x8 qf0 = *(const bf16x8*)(qptr);
    const bf16x8 qf1 = *(const bf16x8*)(qptr + 32);

    f32x4 ot[4] = {};
    float m_i = -INFINITY, l_i = 0.0f;

    for (int k0 = 0; k0 < kend; k0 += 64) {
      char* Kc = Kl[cur];
      char* Vc = Vt[cur];
      if (vstage) {
#pragma unroll
        for (int dj = 0; dj < 4; dj++) {
          const int d = vds + dj;
          u32 lo = (u32)vr[0].a[dj] | ((u32)vr[1].a[dj] << 16);
          u32 hi = (u32)vr[2].a[dj] | ((u32)vr[3].a[dj] << 16);
          const int boff = d * 128 + ((((vrg >> 1) ^ ((d >> 1) & 7)) << 4)) + ((vrg & 1) << 3);
          *(uint2*)(Vc + boff) = make_uint2(lo, hi);
        }
      } else {
        *(uint4*)(Kc + krow * 128 + ((ksl ^ kswzr) << 4)) = kpr0;
        *(uint4*)(Kc + krow * 128 + (((ksl | 4) ^ kswzr) << 4)) = kpr1;
      }
      __syncthreads();

      const int k0n = (k0 + 64 < kend) ? k0 + 64 : 0;
      prefetch(k0n);

      if (k0 <= qw0 + 15) {
        const bool lastT = (k0 + 63 > qw0);
        const int npair = lastT ? (((qw0 + 15 - k0) >> 5) + 1) : 2;

        f32x4 st[4];
#pragma unroll
        for (int ip = 0; ip < 2; ip++)
          if (ip < npair) {
#pragma unroll
            for (int h2 = 0; h2 < 2; h2++) {
              const int kr = 32 * ip + 4 * h2 + kperm;
              const int swzk = (kr & 3) | ((kr & 8) >> 1);
              const char* kro = Kc + kr * 128;
              bf16x8 ka = *(const bf16x8*)(kro + ((g ^ swzk) << 4));
              bf16x8 kb = *(const bf16x8*)(kro + (((g | 4) ^ swzk) << 4));
              f32x4 z = {};
              z = MFMA_BF16(ka, qf0, z, 0, 0, 0);
              st[2 * ip + h2] = MFMA_BF16(kb, qf1, z, 0, 0, 0);
            }
          }

        float p[4][4];
        float mt = -INFINITY;
#pragma unroll
        for (int ip = 0; ip < 2; ip++)
          if (ip < npair) {
#pragma unroll
            for (int h2 = 0; h2 < 2; h2++)
#pragma unroll
              for (int r = 0; r < 4; r++) {
                const int kk = k0 + 32 * ip + 8 * g + 4 * h2 + r;
                float v = (float)st[2 * ip + h2][r] * 0.125f;
                if (lastT && kk > qi) v = -INFINITY;
                p[2 * ip + h2][r] = v;
                mt = fmaxf(mt, v);
              }
          }

        if (!__all(mt - m_i <= 8.0f)) {
          mt = fmaxf(mt, __shfl_xor(mt, 16, 64));
          mt = fmaxf(mt, __shfl_xor(mt, 32, 64));
          const float m_new = fmaxf(m_i, mt);
          const float alpha = __expf(m_i - m_new);
          l_i *= alpha;
#pragma unroll
          for (int dt = 0; dt < 4; dt++)
#pragma unroll
            for (int r = 0; r < 4; r++) ot[dt][r] *= alpha;
          m_i = m_new;
        }
        float s = 0.0f;
#pragma unroll
        for (int ip = 0; ip < 2; ip++)
          if (ip < npair) {
#pragma unroll
            for (int h2 = 0; h2 < 2; h2++)
#pragma unroll
              for (int r = 0; r < 4; r++) {
                float e = __expf(p[2 * ip + h2][r] - m_i);
                p[2 * ip + h2][r] = e;
                s += e;
              }
          }
        l_i += s;

#pragma unroll
        for (int ip = 0; ip < 2; ip++)
          if (ip < npair) {
            bf16x8 pf;
#pragma unroll
            for (int h2 = 0; h2 < 2; h2++)
#pragma unroll
              for (int r = 0; r < 4; r++) pf[4 * h2 + r] = (bf16)p[2 * ip + h2][r];
#pragma unroll
            for (int dt = 0; dt < 4; dt++) {
              const bf16x8 vf = *(const bf16x8*)(
                  Vc + (dt * 16 + l15) * 128 + (((4 * ip + g) ^ (l15 >> 1)) << 4));
              ot[dt] = MFMA_BF16(vf, pf, ot[dt], 0, 0, 0);
            }
          }
      }
      cur ^= 1;
    }

    l_i += __shfl_xor(l_i, 16, 64);
    l_i += __shfl_xor(l_i, 32, 64);
    const float inv = 1.0f / l_i;
    bf16* obase = O + (tokbase + qw0 + l15) * 1024 + hh * 64;
#pragma unroll
    for (int dt = 0; dt < 4; dt++) {
      bf16x4 ov;
#pragma unroll
      for (int r = 0; r < 4; r++) ov[r] = (bf16)(ot[dt][r] * inv);
      *(bf16x4*)(obase + dt * 16 + 4 * g) = ov;
    }
  }
}

// ---------------------------------------------------------------- launch
extern "C" void kernel_launch(void* const* d_in, const int* in_sizes, int n_in,
                              void* d_out, int out_size, void* d_ws, size_t ws_size,
                              hipStream_t stream) {
  const float* x = (const float*)d_in[0];
  const float* w_qkv = (const float*)d_in[1];
  const float* w_out = (const float*)d_in[2];
  const float* w_ff1 = (const float*)d_in[3];
  const float* w_ff2 = (const float*)d_in[4];
  float* out = (float*)d_out;

  char* ws = (char*)d_ws;
  size_t off = 0;
  auto alloc = [&](size_t bytes) {
    void* p = ws + off;
    off += (bytes + 255) & ~(size_t)255;
    return p;
  };
  const size_t M = 8192;
  bf16* X16   = (bf16*)alloc(M * 1024 * 2);
  bf16* WqkvT = (bf16*)alloc(3072ull * 1024 * 2);
  bf16* WoutT = (bf16*)alloc(1024ull * 1024 * 2);
  bf16* Wff1T = (bf16*)alloc(4096ull * 1024 * 2);
  bf16* Wff2T = (bf16*)alloc(1024ull * 4096 * 2);
  bf16* QKV   = (bf16*)alloc(M * 3072 * 2);
  bf16* Obuf  = (bf16*)alloc(M * 1024 * 2);
  bf16* x1b   = (bf16*)alloc(M * 1024 * 2);
  bf16* Hbuf  = (bf16*)alloc(M * 4096 * 2);

  cvt_f32_bf16<<<8192, 256, 0, stream>>>(x, X16, 8192 * 1024);
  transpose_w<<<dim3(3072 / 32, 1024 / 32), 256, 0, stream>>>(w_qkv, WqkvT, 1024, 3072);
  transpose_w<<<dim3(1024 / 32, 1024 / 32), 256, 0, stream>>>(w_out, WoutT, 1024, 1024);
  transpose_w<<<dim3(4096 / 32, 1024 / 32), 256, 0, stream>>>(w_ff1, Wff1T, 1024, 4096);
  transpose_w<<<dim3(1024 / 32, 4096 / 32), 256, 0, stream>>>(w_ff2, Wff2T, 4096, 1024);

  // grids: MT*NT blocks (MT = 8192/BM), XCD-chunked + supertile order
  gemm_bt<0, 128><<<32 * 24, 256, 0, stream>>>(X16, WqkvT, QKV, nullptr, nullptr, nullptr, 1024, 3072);
  attn_fwd<<<dim3(64, 8), 512, 0, stream>>>(QKV, Obuf);
  gemm_bt<1, 64><<<64 * 8, 256, 0, stream>>>(Obuf, WoutT, x1b, nullptr, x, nullptr, 1024, 1024);
  gemm_bt<2, 128><<<32 * 32, 256, 0, stream>>>(x1b, Wff1T, Hbuf, nullptr, nullptr, nullptr, 1024, 4096);
  gemm_bt<3, 64><<<64 * 8, 256, 0, stream>>>(Hbuf, Wff2T, nullptr, out, nullptr, x1b, 4096, 1024);
}